// Round 9
// baseline (285.338 us; speedup 1.0000x reference)
//
#include <hip/hip_runtime.h>
#include <hip/hip_bf16.h>

namespace {

constexpr int kN = 8192;
constexpr float kScale = 0.35355339059327373f;  // 1/sqrt(D=8)

typedef __attribute__((ext_vector_type(8))) short short8;
typedef __attribute__((ext_vector_type(4))) float f32x4;
using uint = unsigned int;

// HW bf16 RNE: scalar casts -> compiler fuses pairs into v_cvt_pk_bf16_f32
__device__ __forceinline__ uint pack2(float lo, float hi) {
  const unsigned short a =
      __builtin_bit_cast(unsigned short, __float2bfloat16(lo));
  const unsigned short b =
      __builtin_bit_cast(unsigned short, __float2bfloat16(hi));
  return (uint)a | ((uint)b << 16);
}
__device__ __forceinline__ float sx(float v, int m) {
  return __shfl_xor(v, m, 64);
}

// R4's proven envelope (58.9us: VGPR 64 + AGPR 64, zero scratch) with exactly
// two changes:
//  1. deferred full-line epilogue (R4 wrote 16B partial lines per iteration ->
//     2x write amplification; now one float4/thread completes 64B lines),
//     which also removes 7 of 8 barriers.
//  2. #pragma unroll 1 on the point loop: the anti-hoist fence. R5-R8 all
//     regressed by letting cross-iteration gather live ranges grow (allocator
//     spills -> 100-300MB scratch traffic). Short per-iteration live ranges
//     are the invariant that must be protected.
// Point->wave interleave pl = i*4+wave kept: adjacent waves gather adjacent
// 128B segments in lockstep (L2 coherence).
__global__ __launch_bounds__(256, 4) void ca_mfma7(
    const float* __restrict__ pcd, const float* __restrict__ nbr,
    const float* __restrict__ q_w, const float* __restrict__ k_w,
    const float* __restrict__ v_w, float* __restrict__ out) {
  __shared__ alignas(16) ushort w_lds[2][64][64];  // [W][o][c] bf16, swizzled
  __shared__ alignas(16) float q_lds[16 * 68];     // [point][o], pre-scaled
  __shared__ alignas(16) float x_lds[16 * 68];     // [point][o]

  const int t = threadIdx.x, wave = t >> 6, lane = t & 63;
  const int l15 = lane & 15, g = lane >> 4;
  const int chunk = blockIdx.x;
  const int b = chunk >> 9;  // 512 chunks per batch
  const int n0 = (chunk & 511) * 16;

  const float* nbase = nbr + (size_t)b * 16777216;  // [c][n][k], c-stride 262144

  // ---- stage k_w/v_w as swizzled bf16 A-tiles (1024 tasks, 4/thread) ----
#pragma unroll
  for (int it = 0; it < 4; ++it) {
    const int task = it * 256 + t;
    const int W = task >> 9, m = (task >> 3) & 63, c0 = (task & 7) * 8;
    const float* src = (W ? v_w : k_w) + m * 64 + c0;
    const float4 a = *(const float4*)src;
    const float4 c = *(const float4*)(src + 4);
    const uint4 pk = make_uint4(pack2(a.x, a.y), pack2(a.z, a.w),
                                pack2(c.x, c.y), pack2(c.z, c.w));
    *(uint4*)((char*)&w_lds[W][m][0] + ((c0 * 2) ^ ((m & 7) << 4))) = pk;
  }

  // ---- wave 0: q = (kScale*q_w) * pcd for all 16 points via MFMA ----
  if (wave == 0) {
    short8 bp[2];  // B: lane l15 = point, elems = c
#pragma unroll
    for (int ks = 0; ks < 2; ++ks) {
      float pv[8];
#pragma unroll
      for (int j = 0; j < 8; ++j)
        pv[j] = pcd[((size_t)b * 64 + ks * 32 + g * 8 + j) * kN + n0 + l15];
      const uint4 u = make_uint4(pack2(pv[0], pv[1]), pack2(pv[2], pv[3]),
                                 pack2(pv[4], pv[5]), pack2(pv[6], pv[7]));
      bp[ks] = *(const short8*)&u;
    }
    f32x4 cq[4] = {};
#pragma unroll
    for (int ks = 0; ks < 2; ++ks) {
#pragma unroll
      for (int mt = 0; mt < 4; ++mt) {
        const float* qs = q_w + (mt * 16 + l15) * 64 + ks * 32 + g * 8;
        const float4 qa = *(const float4*)qs;
        const float4 qb = *(const float4*)(qs + 4);
        const uint4 u = make_uint4(pack2(qa.x * kScale, qa.y * kScale),
                                   pack2(qa.z * kScale, qa.w * kScale),
                                   pack2(qb.x * kScale, qb.y * kScale),
                                   pack2(qb.z * kScale, qb.w * kScale));
        const short8 aq = *(const short8*)&u;
        cq[mt] =
            __builtin_amdgcn_mfma_f32_16x16x32_bf16(aq, bp[ks], cq[mt], 0, 0, 0);
      }
    }
    // C: lane holds q[o = mt*16 + g*4 + r][point = l15]
#pragma unroll
    for (int mt = 0; mt < 4; ++mt)
      *(f32x4*)&q_lds[l15 * 68 + mt * 16 + g * 4] = cq[mt];
  }
  __syncthreads();  // barrier #1 (next one is pre-epilogue)

  const int swz = (l15 & 7) << 4;

  // ---- 4 iterations; wave w owns point n0 + i*4 + w (interleaved) ----
#pragma unroll 1
  for (int i = 0; i < 4; ++i) {
    const int pl = i * 4 + wave;
    const float* nb = nbase + (size_t)(n0 + pl) * 32;

    // gather this point's 64x32 neighbor tile as B-fragment sources
    float bl[2][2][8];  // [ks][nt][j], const-indexed register array
#pragma unroll
    for (int ks = 0; ks < 2; ++ks)
#pragma unroll
      for (int nt = 0; nt < 2; ++nt)
#pragma unroll
        for (int j = 0; j < 8; ++j)
          bl[ks][nt][j] =
              nb[(size_t)(ks * 32 + g * 8 + j) * 262144 + nt * 16 + l15];

    // q fragments (broadcast LDS reads, 4 addrs/wave)
    f32x4 qv[4];
#pragma unroll
    for (int mt = 0; mt < 4; ++mt)
      qv[mt] = *(const f32x4*)&q_lds[pl * 68 + mt * 16 + g * 4];

    // pack B fragments (HW cvt_pk)
    short8 bf[2][2];
#pragma unroll
    for (int ks = 0; ks < 2; ++ks)
#pragma unroll
      for (int nt = 0; nt < 2; ++nt) {
        const uint4 u = make_uint4(pack2(bl[ks][nt][0], bl[ks][nt][1]),
                                   pack2(bl[ks][nt][2], bl[ks][nt][3]),
                                   pack2(bl[ks][nt][4], bl[ks][nt][5]),
                                   pack2(bl[ks][nt][6], bl[ks][nt][7]));
        bf[ks][nt] = *(const short8*)&u;
      }

    // K and V projection GEMMs
    f32x4 accK[2][4] = {};
    f32x4 accV[2][4] = {};
    __builtin_amdgcn_s_setprio(1);
#pragma unroll
    for (int ks = 0; ks < 2; ++ks) {
      const int cb = ks * 64 + g * 16;
#pragma unroll
      for (int W = 0; W < 2; ++W)
#pragma unroll
        for (int mt = 0; mt < 4; ++mt) {
          const short8 af = *(const short8*)(
              (const char*)&w_lds[W][mt * 16 + l15][0] + (cb ^ swz));
#pragma unroll
          for (int nt = 0; nt < 2; ++nt) {
            f32x4& acc = W ? accV[nt][mt] : accK[nt][mt];
            acc = __builtin_amdgcn_mfma_f32_16x16x32_bf16(af, bf[ks][nt], acc,
                                                          0, 0, 0);
          }
        }
    }
    __builtin_amdgcn_s_setprio(0);

    // C layout: lane holds C[m = mt*16 + g*4 + r][k = nt*16 + l15]
    // energy + exp (no max-sub: unit-normal inputs keep |e| small; exact math)
    float p_[4][2], ps[4];
#pragma unroll
    for (int mt = 0; mt < 4; ++mt) {
#pragma unroll
      for (int nt = 0; nt < 2; ++nt) {
        float part = qv[mt].x * accK[nt][mt][0] + qv[mt].y * accK[nt][mt][1] +
                     qv[mt].z * accK[nt][mt][2] + qv[mt].w * accK[nt][mt][3];
        p_[mt][nt] = __expf(part + sx(part, 16));  // d-halves meet at g^1
      }
      ps[mt] = p_[mt][0] + p_[mt][1];
    }

    // denominator fold: 4 sums over 16 lanes; lane ends with its head's sum
    const bool b8 = (l15 & 8) != 0, b4 = (l15 & 4) != 0;
    float s0 = (b8 ? ps[2] : ps[0]) + sx(b8 ? ps[0] : ps[2], 8);
    float s1 = (b8 ? ps[3] : ps[1]) + sx(b8 ? ps[1] : ps[3], 8);
    float sm = (b4 ? s1 : s0) + sx(b4 ? s0 : s1, 4);
    sm += sx(sm, 2);
    sm += sx(sm, 1);

    // PV (unnormalized) then 16->1 fold
    float xv[16];
#pragma unroll
    for (int mt = 0; mt < 4; ++mt)
#pragma unroll
      for (int r = 0; r < 4; ++r)
        xv[mt * 4 + r] =
            p_[mt][0] * accV[0][mt][r] + p_[mt][1] * accV[1][mt][r];
    float a8[8];
#pragma unroll
    for (int j = 0; j < 8; ++j)
      a8[j] = (b8 ? xv[j + 8] : xv[j]) + sx(b8 ? xv[j] : xv[j + 8], 8);
    float a4[4];
#pragma unroll
    for (int j = 0; j < 4; ++j)
      a4[j] = (b4 ? a8[j + 4] : a8[j]) + sx(b4 ? a8[j] : a8[j + 4], 4);
    const bool b2 = (l15 & 2) != 0, b1 = (l15 & 1) != 0;
    float a2[2];
#pragma unroll
    for (int j = 0; j < 2; ++j)
      a2[j] = (b2 ? a4[j + 2] : a4[j]) + sx(b2 ? a4[j] : a4[j + 2], 2);
    const float x1 = (b1 ? a2[1] : a2[0]) + sx(b1 ? a2[0] : a2[1], 1);

    // lane holds x[m=(l15>>2)*16+g*4+(l15&3)]; wave-private row, no barrier
    x_lds[pl * 68 + (l15 >> 2) * 16 + g * 4 + (l15 & 3)] =
        x1 * __builtin_amdgcn_rcpf(sm);
  }

  __syncthreads();  // barrier #2: cross-wave output transpose

  // ---- epilogue: full-line stores; (o,seg) -> float4 over n ----
  {
    const int o = t >> 2, seg = t & 3;
    float4 r;
    r.x = x_lds[(seg * 4 + 0) * 68 + o];
    r.y = x_lds[(seg * 4 + 1) * 68 + o];
    r.z = x_lds[(seg * 4 + 2) * 68 + o];
    r.w = x_lds[(seg * 4 + 3) * 68 + o];
    *(float4*)&out[((size_t)b * 64 + o) * kN + n0 + seg * 4] = r;
  }
}

}  // namespace

extern "C" void kernel_launch(void* const* d_in, const int* in_sizes, int n_in,
                              void* d_out, int out_size, void* d_ws,
                              size_t ws_size, hipStream_t stream) {
  const float* pcd = (const float*)d_in[0];
  const float* nbr = (const float*)d_in[1];
  const float* q_w = (const float*)d_in[2];
  const float* k_w = (const float*)d_in[3];
  const float* v_w = (const float*)d_in[4];
  float* out = (float*)d_out;

  const dim3 grid(2048);  // 32768 points / 16 per WG
  const dim3 block(256);
  hipLaunchKernelGGL(ca_mfma7, grid, block, 0, stream, pcd, nbr, q_w, k_w, v_w,
                     out);
}

// Round 10
// 54.854 us; speedup vs baseline: 5.2018x; 5.2018x over previous
//
#include <hip/hip_runtime.h>
#include <hip/hip_bf16.h>

namespace {

constexpr int kN = 8192;
constexpr float kScale = 0.35355339059327373f;  // 1/sqrt(D=8)

typedef __attribute__((ext_vector_type(8))) short short8;
typedef __attribute__((ext_vector_type(4))) float f32x4;
using uint = unsigned int;

// HW bf16 RNE: scalar casts -> compiler fuses pairs into v_cvt_pk_bf16_f32
__device__ __forceinline__ uint pack2(float lo, float hi) {
  const unsigned short a =
      __builtin_bit_cast(unsigned short, __float2bfloat16(lo));
  const unsigned short b =
      __builtin_bit_cast(unsigned short, __float2bfloat16(hi));
  return (uint)a | ((uint)b << 16);
}
__device__ __forceinline__ float sx(float v, int m) {
  return __shfl_xor(v, m, 64);
}

// R4 verbatim (the proven 58.9us envelope: full-unrolled 4-iter loop,
// pl = i*4+wave interleave, per-iteration __syncthreads) with ONE change:
// the epilogue. R4 stored 16B partial lines each iteration (2x write
// amplification + 4 extra barriers + per-iter LDS transpose). Now x is
// buffered in wave-private x_lds rows and written once, full 64B lines.
// The per-iteration barrier is KEPT deliberately: it is the scheduling
// fence that prevents cross-iteration gather hoisting (R5-R9: every
// weakening of it produced 100-580MB of scratch traffic) and keeps the
// 4 waves' gathers on consecutive 128B lines (DRAM locality).
__global__ __launch_bounds__(256, 4) void ca_mfma8(
    const float* __restrict__ pcd, const float* __restrict__ nbr,
    const float* __restrict__ q_w, const float* __restrict__ k_w,
    const float* __restrict__ v_w, float* __restrict__ out) {
  __shared__ alignas(16) ushort w_lds[2][64][64];  // [W][o][c] bf16, swizzled
  __shared__ alignas(16) float q_lds[16 * 68];     // [point][o], pre-scaled
  __shared__ alignas(16) float x_lds[16][68];      // [point][o]

  const int t = threadIdx.x, wave = t >> 6, lane = t & 63;
  const int l15 = lane & 15, g = lane >> 4;
  const int chunk = blockIdx.x;
  const int b = chunk >> 9;  // 512 chunks per batch
  const int n0 = (chunk & 511) * 16;

  // ---- one-time: stage k_w/v_w to LDS (1024 tasks, 4 per thread) ----
#pragma unroll
  for (int it = 0; it < 4; ++it) {
    const int task = it * 256 + t;
    const int W = task >> 9, m = (task >> 3) & 63, c0 = (task & 7) * 8;
    const float* src = (W ? v_w : k_w) + m * 64 + c0;
    const float4 a = *(const float4*)src;
    const float4 c = *(const float4*)(src + 4);
    const uint4 pk = make_uint4(pack2(a.x, a.y), pack2(a.z, a.w),
                                pack2(c.x, c.y), pack2(c.z, c.w));
    *(uint4*)((char*)&w_lds[W][m][0] + ((c0 * 2) ^ ((m & 7) << 4))) = pk;
  }

  // ---- one-time (wave 0): q = (kScale*q_w) * pcd for 16 points via MFMA ----
  if (wave == 0) {
    short8 bp[2];  // B: lane l15 = point, elems c = ks*32+g*8+j
#pragma unroll
    for (int ks = 0; ks < 2; ++ks) {
      float pv[8];
#pragma unroll
      for (int j = 0; j < 8; ++j)
        pv[j] = pcd[((size_t)b * 64 + ks * 32 + g * 8 + j) * kN + n0 + l15];
      const uint4 u = make_uint4(pack2(pv[0], pv[1]), pack2(pv[2], pv[3]),
                                 pack2(pv[4], pv[5]), pack2(pv[6], pv[7]));
      bp[ks] = *(const short8*)&u;
    }
    f32x4 cq[4] = {};
#pragma unroll
    for (int ks = 0; ks < 2; ++ks) {
#pragma unroll
      for (int mt = 0; mt < 4; ++mt) {
        const float* qs = q_w + (mt * 16 + l15) * 64 + ks * 32 + g * 8;
        const float4 qa = *(const float4*)qs;
        const float4 qb = *(const float4*)(qs + 4);
        const uint4 u = make_uint4(pack2(qa.x * kScale, qa.y * kScale),
                                   pack2(qa.z * kScale, qa.w * kScale),
                                   pack2(qb.x * kScale, qb.y * kScale),
                                   pack2(qb.z * kScale, qb.w * kScale));
        const short8 aq = *(const short8*)&u;
        cq[mt] =
            __builtin_amdgcn_mfma_f32_16x16x32_bf16(aq, bp[ks], cq[mt], 0, 0, 0);
      }
    }
    // C: lane holds q[o = mt*16 + g*4 + r][point = l15]
#pragma unroll
    for (int mt = 0; mt < 4; ++mt)
      *(f32x4*)&q_lds[l15 * 68 + mt * 16 + g * 4] = cq[mt];
  }
  __syncthreads();

  // ---- 4 iterations; wave w owns point n0 + i*4 + w ----
  for (int i = 0; i < 4; ++i) {
    const int pl = i * 4 + wave;
    const int n = n0 + pl;

    // gather this point's 64x32 neighbor tile as B-fragment sources
    float bl[2][2][8];
    const size_t pb = (size_t)b * 16777216 + (size_t)n * 32;
#pragma unroll
    for (int ks = 0; ks < 2; ++ks)
#pragma unroll
      for (int nt = 0; nt < 2; ++nt)
#pragma unroll
        for (int j = 0; j < 8; ++j)
          bl[ks][nt][j] =
              nbr[pb + (size_t)(ks * 32 + g * 8 + j) * 262144 + nt * 16 + l15];

    // q fragments (broadcast LDS reads, 4 addrs/wave)
    f32x4 qv[4];
#pragma unroll
    for (int mt = 0; mt < 4; ++mt)
      qv[mt] = *(const f32x4*)&q_lds[pl * 68 + mt * 16 + g * 4];

    short8 bf[2][2];
#pragma unroll
    for (int ks = 0; ks < 2; ++ks)
#pragma unroll
      for (int nt = 0; nt < 2; ++nt) {
        const uint4 u = make_uint4(pack2(bl[ks][nt][0], bl[ks][nt][1]),
                                   pack2(bl[ks][nt][2], bl[ks][nt][3]),
                                   pack2(bl[ks][nt][4], bl[ks][nt][5]),
                                   pack2(bl[ks][nt][6], bl[ks][nt][7]));
        bf[ks][nt] = *(const short8*)&u;
      }

    // K and V projection GEMMs
    f32x4 accK[2][4] = {};
    f32x4 accV[2][4] = {};
    __builtin_amdgcn_s_setprio(1);
#pragma unroll
    for (int ks = 0; ks < 2; ++ks) {
      const int cb = ks * 64 + g * 16;
      const int swz = (l15 & 7) << 4;
#pragma unroll
      for (int W = 0; W < 2; ++W)
#pragma unroll
        for (int mt = 0; mt < 4; ++mt) {
          const short8 af = *(const short8*)(
              (const char*)&w_lds[W][mt * 16 + l15][0] + (cb ^ swz));
#pragma unroll
          for (int nt = 0; nt < 2; ++nt) {
            f32x4& acc = W ? accV[nt][mt] : accK[nt][mt];
            acc = __builtin_amdgcn_mfma_f32_16x16x32_bf16(af, bf[ks][nt], acc,
                                                          0, 0, 0);
          }
        }
    }
    __builtin_amdgcn_s_setprio(0);

    // C layout: lane holds C[m = mt*16 + g*4 + r][k = nt*16 + l15]
    // energy + exp (no max-sub: unit-normal inputs keep |e| small; exact math)
    float p_[4][2], ps[4];
#pragma unroll
    for (int mt = 0; mt < 4; ++mt) {
#pragma unroll
      for (int nt = 0; nt < 2; ++nt) {
        float part = qv[mt].x * accK[nt][mt][0] + qv[mt].y * accK[nt][mt][1] +
                     qv[mt].z * accK[nt][mt][2] + qv[mt].w * accK[nt][mt][3];
        p_[mt][nt] = __expf(part + sx(part, 16));  // d-halves meet at g^1
      }
      ps[mt] = p_[mt][0] + p_[mt][1];
    }

    // denominator fold: 4 sums over 16 lanes -> lane holds its head's sum
    const bool b8 = (l15 & 8) != 0, b4 = (l15 & 4) != 0;
    float s0 = (b8 ? ps[2] : ps[0]) + sx(b8 ? ps[0] : ps[2], 8);
    float s1 = (b8 ? ps[3] : ps[1]) + sx(b8 ? ps[1] : ps[3], 8);
    float sm = (b4 ? s1 : s0) + sx(b4 ? s0 : s1, 4);
    sm += sx(sm, 2);
    sm += sx(sm, 1);

    // PV (unnormalized), then fold 16 values over 16 lanes
    float xv[16];
#pragma unroll
    for (int mt = 0; mt < 4; ++mt)
#pragma unroll
      for (int r = 0; r < 4; ++r)
        xv[mt * 4 + r] =
            p_[mt][0] * accV[0][mt][r] + p_[mt][1] * accV[1][mt][r];
    float a8[8];
#pragma unroll
    for (int j = 0; j < 8; ++j)
      a8[j] = (b8 ? xv[j + 8] : xv[j]) + sx(b8 ? xv[j] : xv[j + 8], 8);
    float a4[4];
#pragma unroll
    for (int j = 0; j < 4; ++j)
      a4[j] = (b4 ? a8[j + 4] : a8[j]) + sx(b4 ? a8[j] : a8[j + 4], 4);
    const bool b2 = (l15 & 2) != 0, b1 = (l15 & 1) != 0;
    float a2[2];
#pragma unroll
    for (int j = 0; j < 2; ++j)
      a2[j] = (b2 ? a4[j + 2] : a4[j]) + sx(b2 ? a4[j] : a4[j + 2], 2);
    const float x1 = (b1 ? a2[1] : a2[0]) + sx(b1 ? a2[0] : a2[1], 1);

    // lane holds x[m = (l15>>2)*16 + g*4 + (l15&3)]; wave-private row
    x_lds[pl][(l15 >> 2) * 16 + g * 4 + (l15 & 3)] =
        x1 * __builtin_amdgcn_rcpf(sm);

    __syncthreads();  // scheduling fence: no gather hoisting, waves lockstep
  }

  // ---- epilogue: full-line stores; (o,seg) -> float4 over n ----
  {
    const int o = t >> 2, seg = t & 3;
    float4 r;
    r.x = x_lds[seg * 4 + 0][o];
    r.y = x_lds[seg * 4 + 1][o];
    r.z = x_lds[seg * 4 + 2][o];
    r.w = x_lds[seg * 4 + 3][o];
    *(float4*)&out[((size_t)b * 64 + o) * kN + n0 + seg * 4] = r;
  }
}

}  // namespace

extern "C" void kernel_launch(void* const* d_in, const int* in_sizes, int n_in,
                              void* d_out, int out_size, void* d_ws,
                              size_t ws_size, hipStream_t stream) {
  const float* pcd = (const float*)d_in[0];
  const float* nbr = (const float*)d_in[1];
  const float* q_w = (const float*)d_in[2];
  const float* k_w = (const float*)d_in[3];
  const float* v_w = (const float*)d_in[4];
  float* out = (float*)d_out;

  const dim3 grid(2048);  // 32768 points / 16 per WG
  const dim3 block(256);
  hipLaunchKernelGGL(ca_mfma8, grid, block, 0, stream, pcd, nbr, q_w, k_w, v_w,
                     out);
}

// Round 11
// 54.580 us; speedup vs baseline: 5.2279x; 1.0050x over previous
//
#include <hip/hip_runtime.h>
#include <hip/hip_bf16.h>

namespace {

constexpr int kN = 8192;
constexpr float kScale = 0.35355339059327373f;  // 1/sqrt(D=8)

typedef __attribute__((ext_vector_type(8))) short short8;
typedef __attribute__((ext_vector_type(4))) float f32x4;
using uint = unsigned int;

// HW bf16 RNE: scalar casts -> compiler fuses pairs into v_cvt_pk_bf16_f32
__device__ __forceinline__ uint pack2(float lo, float hi) {
  const unsigned short a =
      __builtin_bit_cast(unsigned short, __float2bfloat16(lo));
  const unsigned short b =
      __builtin_bit_cast(unsigned short, __float2bfloat16(hi));
  return (uint)a | ((uint)b << 16);
}
__device__ __forceinline__ float sx(float v, int m) {
  return __shfl_xor(v, m, 64);
}

// R10 (54.9us proven envelope) + ONE change: phased K/V GEMMs so only one
// 32-reg accumulator array is live at a time. That cuts peak regs from
// 128 (64 VGPR + 64 AGPR, 4 waves/SIMD) to ~97, and __launch_bounds__(256,5)
// caps allocation at 102 -> 5 WGs/CU (20 waves/CU, +25% TLP) with LDS at
// 25KB (6 WG-capable). The latency model says 4 waves/SIMD is right at the
// hiding margin for the ~900cy gather window; the 5th wave tips it over.
// Kept deliberately from R10 (each violated once in R5-R9, each time a
// regression): per-iteration __syncthreads fence, pl = i*4+wave interleave,
// NO cross-point register prefetch, deferred full-line epilogue.
__global__ __launch_bounds__(256, 5) void ca_mfma9(
    const float* __restrict__ pcd, const float* __restrict__ nbr,
    const float* __restrict__ q_w, const float* __restrict__ k_w,
    const float* __restrict__ v_w, float* __restrict__ out) {
  __shared__ alignas(16) ushort w_lds[2][64][64];  // [W][o][c] bf16, swizzled
  __shared__ alignas(16) float q_lds[16 * 68];     // [point][o], pre-scaled
  __shared__ alignas(16) float x_lds[16][68];      // [point][o]

  const int t = threadIdx.x, wave = t >> 6, lane = t & 63;
  const int l15 = lane & 15, g = lane >> 4;
  const int chunk = blockIdx.x;
  const int b = chunk >> 9;  // 512 chunks per batch
  const int n0 = (chunk & 511) * 16;

  // ---- one-time: stage k_w/v_w to LDS (1024 tasks, 4 per thread) ----
#pragma unroll
  for (int it = 0; it < 4; ++it) {
    const int task = it * 256 + t;
    const int W = task >> 9, m = (task >> 3) & 63, c0 = (task & 7) * 8;
    const float* src = (W ? v_w : k_w) + m * 64 + c0;
    const float4 a = *(const float4*)src;
    const float4 c = *(const float4*)(src + 4);
    const uint4 pk = make_uint4(pack2(a.x, a.y), pack2(a.z, a.w),
                                pack2(c.x, c.y), pack2(c.z, c.w));
    *(uint4*)((char*)&w_lds[W][m][0] + ((c0 * 2) ^ ((m & 7) << 4))) = pk;
  }

  // ---- one-time (wave 0): q = (kScale*q_w) * pcd for 16 points via MFMA ----
  if (wave == 0) {
    short8 bp[2];  // B: lane l15 = point, elems c = ks*32+g*8+j
#pragma unroll
    for (int ks = 0; ks < 2; ++ks) {
      float pv[8];
#pragma unroll
      for (int j = 0; j < 8; ++j)
        pv[j] = pcd[((size_t)b * 64 + ks * 32 + g * 8 + j) * kN + n0 + l15];
      const uint4 u = make_uint4(pack2(pv[0], pv[1]), pack2(pv[2], pv[3]),
                                 pack2(pv[4], pv[5]), pack2(pv[6], pv[7]));
      bp[ks] = *(const short8*)&u;
    }
    f32x4 cq[4] = {};
#pragma unroll
    for (int ks = 0; ks < 2; ++ks) {
#pragma unroll
      for (int mt = 0; mt < 4; ++mt) {
        const float* qs = q_w + (mt * 16 + l15) * 64 + ks * 32 + g * 8;
        const float4 qa = *(const float4*)qs;
        const float4 qb = *(const float4*)(qs + 4);
        const uint4 u = make_uint4(pack2(qa.x * kScale, qa.y * kScale),
                                   pack2(qa.z * kScale, qa.w * kScale),
                                   pack2(qb.x * kScale, qb.y * kScale),
                                   pack2(qb.z * kScale, qb.w * kScale));
        const short8 aq = *(const short8*)&u;
        cq[mt] =
            __builtin_amdgcn_mfma_f32_16x16x32_bf16(aq, bp[ks], cq[mt], 0, 0, 0);
      }
    }
    // C: lane holds q[o = mt*16 + g*4 + r][point = l15]
#pragma unroll
    for (int mt = 0; mt < 4; ++mt)
      *(f32x4*)&q_lds[l15 * 68 + mt * 16 + g * 4] = cq[mt];
  }
  __syncthreads();

  // ---- 4 iterations; wave w owns point n0 + i*4 + w ----
  for (int i = 0; i < 4; ++i) {
    const int pl = i * 4 + wave;
    const int n = n0 + pl;

    // gather this point's 64x32 neighbor tile as B-fragment sources
    float bl[2][2][8];
    const size_t pb = (size_t)b * 16777216 + (size_t)n * 32;
#pragma unroll
    for (int ks = 0; ks < 2; ++ks)
#pragma unroll
      for (int nt = 0; nt < 2; ++nt)
#pragma unroll
        for (int j = 0; j < 8; ++j)
          bl[ks][nt][j] =
              nbr[pb + (size_t)(ks * 32 + g * 8 + j) * 262144 + nt * 16 + l15];

    short8 bf[2][2];
#pragma unroll
    for (int ks = 0; ks < 2; ++ks)
#pragma unroll
      for (int nt = 0; nt < 2; ++nt) {
        const uint4 u = make_uint4(pack2(bl[ks][nt][0], bl[ks][nt][1]),
                                   pack2(bl[ks][nt][2], bl[ks][nt][3]),
                                   pack2(bl[ks][nt][4], bl[ks][nt][5]),
                                   pack2(bl[ks][nt][6], bl[ks][nt][7]));
        bf[ks][nt] = *(const short8*)&u;
      }

    const int swz = (l15 & 7) << 4;

    // ---- phase 1: K projection GEMM (only accK live) ----
    f32x4 accK[2][4] = {};
    __builtin_amdgcn_s_setprio(1);
#pragma unroll
    for (int ks = 0; ks < 2; ++ks) {
      const int cb = ks * 64 + g * 16;
#pragma unroll
      for (int mt = 0; mt < 4; ++mt) {
        const short8 af = *(const short8*)(
            (const char*)&w_lds[0][mt * 16 + l15][0] + (cb ^ swz));
#pragma unroll
        for (int nt = 0; nt < 2; ++nt)
          accK[nt][mt] = __builtin_amdgcn_mfma_f32_16x16x32_bf16(
              af, bf[ks][nt], accK[nt][mt], 0, 0, 0);
      }
    }
    __builtin_amdgcn_s_setprio(0);

    // C layout: lane holds C[m = mt*16 + g*4 + r][k = nt*16 + l15]
    // energy + exp (no max-sub: unit-normal inputs keep |e| small; exact math)
    float p_[4][2], ps[4];
#pragma unroll
    for (int mt = 0; mt < 4; ++mt) {
      const f32x4 qv = *(const f32x4*)&q_lds[pl * 68 + mt * 16 + g * 4];
#pragma unroll
      for (int nt = 0; nt < 2; ++nt) {
        float part = qv.x * accK[nt][mt][0] + qv.y * accK[nt][mt][1] +
                     qv.z * accK[nt][mt][2] + qv.w * accK[nt][mt][3];
        p_[mt][nt] = __expf(part + sx(part, 16));  // d-halves meet at g^1
      }
      ps[mt] = p_[mt][0] + p_[mt][1];
    }
    // accK dead from here -> the V accumulator reuses its registers

    // denominator fold: 4 sums over 16 lanes -> lane holds its head's sum
    const bool b8 = (l15 & 8) != 0, b4 = (l15 & 4) != 0;
    float s0 = (b8 ? ps[2] : ps[0]) + sx(b8 ? ps[0] : ps[2], 8);
    float s1 = (b8 ? ps[3] : ps[1]) + sx(b8 ? ps[1] : ps[3], 8);
    float sm = (b4 ? s1 : s0) + sx(b4 ? s0 : s1, 4);
    sm += sx(sm, 2);
    sm += sx(sm, 1);

    // ---- phase 2: V projection GEMM (reuses accumulator registers) ----
    f32x4 accV[2][4] = {};
    __builtin_amdgcn_s_setprio(1);
#pragma unroll
    for (int ks = 0; ks < 2; ++ks) {
      const int cb = ks * 64 + g * 16;
#pragma unroll
      for (int mt = 0; mt < 4; ++mt) {
        const short8 af = *(const short8*)(
            (const char*)&w_lds[1][mt * 16 + l15][0] + (cb ^ swz));
#pragma unroll
        for (int nt = 0; nt < 2; ++nt)
          accV[nt][mt] = __builtin_amdgcn_mfma_f32_16x16x32_bf16(
              af, bf[ks][nt], accV[nt][mt], 0, 0, 0);
      }
    }
    __builtin_amdgcn_s_setprio(0);

    // PV (unnormalized), then fold 16 values over 16 lanes
    float xv[16];
#pragma unroll
    for (int mt = 0; mt < 4; ++mt)
#pragma unroll
      for (int r = 0; r < 4; ++r)
        xv[mt * 4 + r] =
            p_[mt][0] * accV[0][mt][r] + p_[mt][1] * accV[1][mt][r];
    float a8[8];
#pragma unroll
    for (int j = 0; j < 8; ++j)
      a8[j] = (b8 ? xv[j + 8] : xv[j]) + sx(b8 ? xv[j] : xv[j + 8], 8);
    float a4[4];
#pragma unroll
    for (int j = 0; j < 4; ++j)
      a4[j] = (b4 ? a8[j + 4] : a8[j]) + sx(b4 ? a8[j] : a8[j + 4], 4);
    const bool b2 = (l15 & 2) != 0, b1 = (l15 & 1) != 0;
    float a2[2];
#pragma unroll
    for (int j = 0; j < 2; ++j)
      a2[j] = (b2 ? a4[j + 2] : a4[j]) + sx(b2 ? a4[j] : a4[j + 2], 2);
    const float x1 = (b1 ? a2[1] : a2[0]) + sx(b1 ? a2[0] : a2[1], 1);

    // lane holds x[m = (l15>>2)*16 + g*4 + (l15&3)]; wave-private row
    x_lds[pl][(l15 >> 2) * 16 + g * 4 + (l15 & 3)] =
        x1 * __builtin_amdgcn_rcpf(sm);

    __syncthreads();  // scheduling fence: no gather hoisting, waves lockstep
  }

  // ---- epilogue: full-line stores; (o,seg) -> float4 over n ----
  {
    const int o = t >> 2, seg = t & 3;
    float4 r;
    r.x = x_lds[seg * 4 + 0][o];
    r.y = x_lds[seg * 4 + 1][o];
    r.z = x_lds[seg * 4 + 2][o];
    r.w = x_lds[seg * 4 + 3][o];
    *(float4*)&out[((size_t)b * 64 + o) * kN + n0 + seg * 4] = r;
  }
}

}  // namespace

extern "C" void kernel_launch(void* const* d_in, const int* in_sizes, int n_in,
                              void* d_out, int out_size, void* d_ws,
                              size_t ws_size, hipStream_t stream) {
  const float* pcd = (const float*)d_in[0];
  const float* nbr = (const float*)d_in[1];
  const float* q_w = (const float*)d_in[2];
  const float* k_w = (const float*)d_in[3];
  const float* v_w = (const float*)d_in[4];
  float* out = (float*)d_out;

  const dim3 grid(2048);  // 32768 points / 16 per WG
  const dim3 block(256);
  hipLaunchKernelGGL(ca_mfma9, grid, block, 0, stream, pcd, nbr, q_w, k_w, v_w,
                     out);
}